// Round 3
// baseline (1794.196 us; speedup 1.0000x reference)
//
#include <hip/hip_runtime.h>
#include <hip/hip_bf16.h>

#define B_    2
#define C_    256
#define HW_   56
#define N_    3136     // 56*56
#define NQ_   784      // N_/4 j-quads
#define NH_   8
#define D_    32
#define K1CNT 1568     // N_/2
#define K2CNT 1045     // N_//3
#define LN_EPS 1e-5f
#define SROW  3140     // padded score row (floats); 3140*4B is 16B-aligned, %32==4
#define HSTR  260      // histogram row stride; 260%32==4 -> rows spread across banks

// ---------------- helpers ----------------
__device__ inline unsigned ordf(float f) {
    unsigned u = __float_as_uint(f);
    return u ^ (((unsigned)((int)u >> 31)) | 0x80000000u);
}

// ---------------- pooling (3 avg pools summed, zero-pad, divisor k*k) -------
__global__ void pool_kernel(const float* __restrict__ y, float* __restrict__ yp)
{
    int gid = blockIdx.x * 256 + threadIdx.x;      // b*C*N + c*N + n (n fastest)
    int n  = gid % N_;
    int bc = gid / N_;
    const float* src = y + (size_t)bc * N_;
    int x0 = n % HW_, y0 = n / HW_;
    float acc = 0.f;
#pragma unroll
    for (int dy = -3; dy <= 3; ++dy) {
        int yy = y0 + dy;
        if ((unsigned)yy >= HW_) continue;
#pragma unroll
        for (int dx = -3; dx <= 3; ++dx) {
            int xx = x0 + dx;
            if ((unsigned)xx >= HW_) continue;
            float w = 1.f / 49.f;
            if (dy >= -2 && dy <= 2 && dx >= -2 && dx <= 2) w += 1.f / 25.f;
            if (dy >= -1 && dy <= 1 && dx >= -1 && dx <= 1) w += 1.f / 9.f;
            acc += w * src[yy * HW_ + xx];
        }
    }
    yp[gid] = acc;
}

// ---------------- layernorm over C, writes transposed [B,C,N] ---------------
__global__ void ln_kernel(const float* __restrict__ yp, const float* __restrict__ lnw,
                          const float* __restrict__ lnb, float* __restrict__ yfT)
{
    __shared__ float wr[8];
    __shared__ float stats[2];
    int idx = blockIdx.x;            // b*N + n
    int b = idx / N_, n = idx % N_;
    int c = threadIdx.x;
    size_t off = ((size_t)b * C_ + c) * N_ + n;
    float v = yp[off];
    float s = v, q = v * v;
    int lane = threadIdx.x & 63, wid = threadIdx.x >> 6;
#pragma unroll
    for (int d = 32; d; d >>= 1) { s += __shfl_down(s, d, 64); q += __shfl_down(q, d, 64); }
    if (lane == 0) { wr[wid] = s; wr[4 + wid] = q; }
    __syncthreads();
    if (threadIdx.x == 0) {
        float ts = wr[0] + wr[1] + wr[2] + wr[3];
        float tq = wr[4] + wr[5] + wr[6] + wr[7];
        float mu = ts * (1.f / C_);
        float var = tq * (1.f / C_) - mu * mu;
        stats[0] = mu; stats[1] = rsqrtf(var + LN_EPS);
    }
    __syncthreads();
    yfT[off] = (v - stats[0]) * stats[1] * lnw[c] + lnb[c];
}

// ---------------- GEMM: out = A(AT layout [B,C,N]) @ W[O,K]^T + bias --------
__global__ __launch_bounds__(256) void gemm_qkv(
    const float* __restrict__ A, const float* __restrict__ W,
    const float* __restrict__ bias, float* __restrict__ dst0,
    float* __restrict__ dst1, float scale)
{
    __shared__ float As[16][64];
    __shared__ float Ws[16][68];
    int tid = threadIdx.x;
    int m0 = blockIdx.x * 64;
    int b = m0 / N_, n0 = m0 % N_;
    int o0 = blockIdx.y * 64;
    const float* Ab = A + (size_t)b * C_ * N_;
    float acc[4][4] = {};
    int la_k = tid >> 4;
    int la_m = (tid & 15) * 4;
    int lw_o = tid >> 2;
    int lw_k = (tid & 3) * 4;
    int u  = tid & 15;
    int v_ = tid >> 4;
    for (int kt = 0; kt < 16; ++kt) {
        int k0 = kt * 16;
        float4 av = *(const float4*)&Ab[(size_t)(k0 + la_k) * N_ + n0 + la_m];
        float4 wv = *(const float4*)&W[(size_t)(o0 + lw_o) * C_ + k0 + lw_k];
        __syncthreads();
        *(float4*)&As[la_k][la_m] = av;
        Ws[lw_k + 0][lw_o] = wv.x; Ws[lw_k + 1][lw_o] = wv.y;
        Ws[lw_k + 2][lw_o] = wv.z; Ws[lw_k + 3][lw_o] = wv.w;
        __syncthreads();
#pragma unroll
        for (int k = 0; k < 16; ++k) {
            float4 wf = *(const float4*)&Ws[k][u * 4];
            float a0 = As[k][v_], a1 = As[k][v_ + 16], a2 = As[k][v_ + 32], a3 = As[k][v_ + 48];
            acc[0][0] += wf.x * a0; acc[0][1] += wf.x * a1; acc[0][2] += wf.x * a2; acc[0][3] += wf.x * a3;
            acc[1][0] += wf.y * a0; acc[1][1] += wf.y * a1; acc[1][2] += wf.y * a2; acc[1][3] += wf.y * a3;
            acc[2][0] += wf.z * a0; acc[2][1] += wf.z * a1; acc[2][2] += wf.z * a2; acc[2][3] += wf.z * a3;
            acc[3][0] += wf.w * a0; acc[3][1] += wf.w * a1; acc[3][2] += wf.w * a2; acc[3][3] += wf.w * a3;
        }
    }
    int oc = o0 + u * 4;
    float b0v = bias[oc], b1v = bias[oc + 1], b2v = bias[oc + 2], b3v = bias[oc + 3];
    float* dst = dst0; int c2 = oc;
    if (dst1 && oc >= C_) { dst = dst1; c2 = oc - C_; }
    int h = c2 >> 5, d0 = c2 & 31;
    size_t base = ((size_t)b * NH_ + h) * N_ * D_;
#pragma unroll
    for (int j = 0; j < 4; ++j) {
        int n = n0 + v_ + j * 16;
        float4 val;
        val.x = (acc[0][j] + b0v) * scale;
        val.y = (acc[1][j] + b1v) * scale;
        val.z = (acc[2][j] + b2v) * scale;
        val.w = (acc[3][j] + b3v) * scale;
        *(float4*)&dst[base + (size_t)n * D_ + d0] = val;
    }
}

__global__ __launch_bounds__(256) void gemm_proj(
    const float* __restrict__ A, const float* __restrict__ W,
    const float* __restrict__ bias, float* __restrict__ out)
{
    __shared__ float As[16][64];
    __shared__ float Ws[16][68];
    int tid = threadIdx.x;
    int m0 = blockIdx.x * 64;
    int b = m0 / N_, n0 = m0 % N_;
    int o0 = blockIdx.y * 64;
    const float* Ab = A + (size_t)b * C_ * N_;
    float acc[4][4] = {};
    int la_k = tid >> 4;
    int la_m = (tid & 15) * 4;
    int lw_o = tid >> 2;
    int lw_k = (tid & 3) * 4;
    int u  = tid & 15;
    int v_ = tid >> 4;
    for (int kt = 0; kt < 16; ++kt) {
        int k0 = kt * 16;
        float4 av = *(const float4*)&Ab[(size_t)(k0 + la_k) * N_ + n0 + la_m];
        float4 wv = *(const float4*)&W[(size_t)(o0 + lw_o) * C_ + k0 + lw_k];
        __syncthreads();
        *(float4*)&As[la_k][la_m] = av;
        Ws[lw_k + 0][lw_o] = wv.x; Ws[lw_k + 1][lw_o] = wv.y;
        Ws[lw_k + 2][lw_o] = wv.z; Ws[lw_k + 3][lw_o] = wv.w;
        __syncthreads();
#pragma unroll
        for (int k = 0; k < 16; ++k) {
            float4 af = *(const float4*)&As[k][u * 4];
            float w0 = Ws[k][v_], w1 = Ws[k][v_ + 16], w2 = Ws[k][v_ + 32], w3 = Ws[k][v_ + 48];
            acc[0][0] += w0 * af.x; acc[0][1] += w0 * af.y; acc[0][2] += w0 * af.z; acc[0][3] += w0 * af.w;
            acc[1][0] += w1 * af.x; acc[1][1] += w1 * af.y; acc[1][2] += w1 * af.z; acc[1][3] += w1 * af.w;
            acc[2][0] += w2 * af.x; acc[2][1] += w2 * af.y; acc[2][2] += w2 * af.z; acc[2][3] += w2 * af.w;
            acc[3][0] += w3 * af.x; acc[3][1] += w3 * af.y; acc[3][2] += w3 * af.z; acc[3][3] += w3 * af.w;
        }
    }
#pragma unroll
    for (int i = 0; i < 4; ++i) {
        int o = o0 + v_ + i * 16;
        float bb = bias[o];
        float4 val;
        val.x = acc[i][0] + bb; val.y = acc[i][1] + bb;
        val.z = acc[i][2] + bb; val.w = acc[i][3] + bb;
        *(float4*)&out[((size_t)b * C_ + o) * N_ + n0 + u * 4] = val;
    }
}

// ---------------- fused attention (1024 threads, 16 waves) ----------------
struct AttnMisc {
    float rowmax[8];
    unsigned prefU[16];  // accumulated radix prefix per problem (8 rows x 2 k's)
    int remK[16];        // remaining rank per problem
    float coef[16];
    float pp[2];
    float wred[256];     // 16 waves x 16 slots
};

__global__ __launch_bounds__(1024) void attn_kernel(
    const float* __restrict__ qh, const float* __restrict__ kh, const float* __restrict__ vh,
    const float* __restrict__ p1p, const float* __restrict__ p2p,
    float* __restrict__ aoT)
{
    extern __shared__ char smem[];
    float*    S  = (float*)smem;                       // 8*3140 fp32   (100480 B)
    float*    qs = (float*)(smem + 100480);            // 256 fp32      (1024 B)
    unsigned* hA = (unsigned*)(smem + 101504);         // 16*260 u32    (16640 B)
    unsigned* hB = (unsigned*)(smem + 118144);         // 16*260 u32    (16640 B)
    AttnMisc* M  = (AttnMisc*)(smem + 134784);

    int tid = threadIdx.x, lane = tid & 63, wid = tid >> 6;
    int bh = blockIdx.y, n0 = blockIdx.x * 8;
    size_t bhN = (size_t)bh * N_;

    if (tid < 256) qs[tid] = qh[(bhN + n0) * D_ + tid];
    if (tid < 16) { M->prefU[tid] = 0u; M->remK[tid] = (tid & 1) ? K2CNT : K1CNT; }
    if (tid == 0) { M->pp[0] = p1p[0]; M->pp[1] = p2p[0]; }
    for (int i = tid; i < 16 * HSTR; i += 1024) hA[i] = 0u;
    __syncthreads();

    // ==== P1: scores for a 4-wide j-quad per thread, q reused across 4 j ====
    float lmax[8];
#pragma unroll
    for (int r = 0; r < 8; ++r) lmax[r] = -3.4e38f;
    if (tid < NQ_) {
        int j0 = tid * 4;
        const float* kb = kh + (bhN + j0) * D_;
        float acc[8][4] = {};
#pragma unroll
        for (int c2 = 0; c2 < 4; ++c2) {          // quad-pair chunks of K
            float4 kq[4][2];
#pragma unroll
            for (int jj = 0; jj < 4; ++jj)
#pragma unroll
                for (int qi = 0; qi < 2; ++qi)
                    kq[jj][qi] = *(const float4*)&kb[jj * D_ + c2 * 8 + qi * 4];
#pragma unroll
            for (int r = 0; r < 8; ++r) {
#pragma unroll
                for (int qi = 0; qi < 2; ++qi) {
                    float4 q4 = *(const float4*)&qs[r * D_ + c2 * 8 + qi * 4];
#pragma unroll
                    for (int jj = 0; jj < 4; ++jj) {
                        acc[r][jj] = fmaf(q4.x, kq[jj][qi].x, acc[r][jj]);
                        acc[r][jj] = fmaf(q4.y, kq[jj][qi].y, acc[r][jj]);
                        acc[r][jj] = fmaf(q4.z, kq[jj][qi].z, acc[r][jj]);
                        acc[r][jj] = fmaf(q4.w, kq[jj][qi].w, acc[r][jj]);
                    }
                }
            }
        }
#pragma unroll
        for (int r = 0; r < 8; ++r) {
            *(float4*)&S[r * SROW + j0] = make_float4(acc[r][0], acc[r][1], acc[r][2], acc[r][3]);
#pragma unroll
            for (int jj = 0; jj < 4; ++jj) {
                float a = acc[r][jj];
                lmax[r] = fmaxf(lmax[r], a);
                atomicAdd(&hA[r * HSTR + (ordf(a) >> 24)], 1u);
            }
        }
    }
#pragma unroll
    for (int r = 0; r < 8; ++r) {
        float v = lmax[r];
#pragma unroll
        for (int d = 32; d; d >>= 1) v = fmaxf(v, __shfl_down(v, d, 64));
        if (lane == 0) M->wred[wid * 16 + r] = v;
    }
    __syncthreads();

    // ==== 4-level 8-bit radix select: 16 problems in parallel ====
    for (int lvl = 0; lvl < 4; ++lvl) {
        if (lvl > 0) {
            int shift = 24 - 8 * lvl;
            unsigned pf[16];
#pragma unroll
            for (int p = 0; p < 16; ++p) pf[p] = M->prefU[p];
            unsigned* hcur = (lvl & 1) ? hB : hA;
            if (tid < NQ_) {
                int j0 = tid * 4;
#pragma unroll
                for (int r = 0; r < 8; ++r) {
                    float4 sv = *(const float4*)&S[r * SROW + j0];
                    float e[4] = {sv.x, sv.y, sv.z, sv.w};
#pragma unroll
                    for (int c = 0; c < 4; ++c) {
                        unsigned u = ordf(e[c]);
                        unsigned hi = u >> (shift + 8);
                        unsigned bin = (u >> shift) & 0xFFu;
                        if (hi == pf[r * 2])     atomicAdd(&hcur[(r * 2) * HSTR + bin], 1u);
                        if (hi == pf[r * 2 + 1]) atomicAdd(&hcur[(r * 2 + 1) * HSTR + bin], 1u);
                    }
                }
            }
            __syncthreads();
        }
        {   // search (16 waves, one problem each) + zero the other hist buffer
            unsigned* hcur = (lvl & 1) ? hB : hA;
            unsigned* hoth = (lvl & 1) ? hA : hB;
            if (lvl < 3)
                for (int i = tid; i < 16 * HSTR; i += 1024) hoth[i] = 0u;
            if (lvl == 0 && tid < 8) {
                float mm = -3.4e38f;
                for (int w = 0; w < 16; ++w) mm = fmaxf(mm, M->wred[w * 16 + tid]);
                M->rowmax[tid] = mm;
            }
            int prob = wid;
            const unsigned* hh = hcur + ((lvl == 0) ? (prob >> 1) * HSTR : prob * HSTR);
            int k = M->remK[prob];
            int h0 = (int)hh[lane * 4], h1 = (int)hh[lane * 4 + 1],
                h2 = (int)hh[lane * 4 + 2], h3 = (int)hh[lane * 4 + 3];
            int ls3 = h3, ls2 = ls3 + h2, ls1 = ls2 + h1, ls0 = ls1 + h0;
            int s = ls0;
#pragma unroll
            for (int d = 1; d < 64; d <<= 1) {
                int o = __shfl_down(s, d, 64);
                if (lane + d < 64) s += o;
            }
            int after = s - ls0;     // elements in bins above this lane's 4 bins
            int G0 = ls0 + after, G1 = ls1 + after, G2 = ls2 + after, G3 = ls3 + after;
            int selb = -1, selr = 0;
            if (G0 >= k && G0 - h0 < k) { selb = lane * 4;     selr = k - (G0 - h0); }
            if (G1 >= k && G1 - h1 < k) { selb = lane * 4 + 1; selr = k - (G1 - h1); }
            if (G2 >= k && G2 - h2 < k) { selb = lane * 4 + 2; selr = k - (G2 - h2); }
            if (G3 >= k && G3 - h3 < k) { selb = lane * 4 + 3; selr = k - (G3 - h3); }
            if (selb >= 0) {
                M->prefU[prob] = (M->prefU[prob] << 8) | (unsigned)selb;
                M->remK[prob] = selr;
            }
        }
        __syncthreads();
    }

    // ==== P5: masked exp sums + signed markers (b128 in/out) ====
    unsigned t1r[8], t2r[8]; float rm[8];
#pragma unroll
    for (int r = 0; r < 8; ++r) {
        t1r[r] = M->prefU[r * 2];
        t2r[r] = M->prefU[r * 2 + 1];
        rm[r] = M->rowmax[r];
    }
    float ls1a[8] = {}, ls2a[8] = {};
    if (tid < NQ_) {
        int j0 = tid * 4;
#pragma unroll
        for (int r = 0; r < 8; ++r) {
            float4 sv = *(const float4*)&S[r * SROW + j0];
            float e[4] = {sv.x, sv.y, sv.z, sv.w};
#pragma unroll
            for (int c = 0; c < 4; ++c) {
                float a = e[c];
                unsigned u = ordf(a);
                float outv = 0.f;
                if (u >= t1r[r]) {
                    float w = __expf(a - rm[r]);
                    ls1a[r] += w;
                    if (u >= t2r[r]) { ls2a[r] += w; outv = w; }
                    else outv = -w;
                }
                e[c] = outv;
            }
            *(float4*)&S[r * SROW + j0] = make_float4(e[0], e[1], e[2], e[3]);
        }
    }
#pragma unroll
    for (int r = 0; r < 8; ++r) {
        float a1 = ls1a[r], a2 = ls2a[r];
#pragma unroll
        for (int d = 32; d; d >>= 1) { a1 += __shfl_down(a1, d, 64); a2 += __shfl_down(a2, d, 64); }
        if (lane == 0) { M->wred[wid * 16 + r * 2] = a1; M->wred[wid * 16 + r * 2 + 1] = a2; }
    }
    __syncthreads();
    if (tid < 16) {
        float ssum = 0.f;
        for (int w = 0; w < 16; ++w) ssum += M->wred[w * 16 + tid];
        M->coef[tid] = ((tid & 1) ? M->pp[1] : M->pp[0]) / ssum;
    }
    __syncthreads();

    // ==== AV: V direct from global; S b128 broadcast; coef fused at read ====
    float c12r[8], cn1r[8];
#pragma unroll
    for (int r = 0; r < 8; ++r) {
        float c1 = M->coef[r * 2], c2 = M->coef[r * 2 + 1];
        c12r[r] = c1 + c2;
        cn1r[r] = -c1;
    }
    int dq = tid & 7, g = tid >> 3;          // 128 j-groups x 8 d-quads
    const float* vb = vh + bhN * D_ + dq * 4;
    float acc[8][4] = {};
    for (int p = 0; p < 7; ++p) {
        int jq = p * 128 + g;
        if (jq < NQ_) {
            int j0 = jq * 4;
            float4 v0 = *(const float4*)&vb[(size_t)(j0 + 0) * D_];
            float4 v1 = *(const float4*)&vb[(size_t)(j0 + 1) * D_];
            float4 v2 = *(const float4*)&vb[(size_t)(j0 + 2) * D_];
            float4 v3 = *(const float4*)&vb[(size_t)(j0 + 3) * D_];
#pragma unroll
            for (int r = 0; r < 8; ++r) {
                float4 sv = *(const float4*)&S[r * SROW + j0];
                float c0 = sv.x * ((sv.x > 0.f) ? c12r[r] : cn1r[r]);
                float c1 = sv.y * ((sv.y > 0.f) ? c12r[r] : cn1r[r]);
                float c2 = sv.z * ((sv.z > 0.f) ? c12r[r] : cn1r[r]);
                float c3 = sv.w * ((sv.w > 0.f) ? c12r[r] : cn1r[r]);
                acc[r][0] = fmaf(c0, v0.x, acc[r][0]); acc[r][1] = fmaf(c0, v0.y, acc[r][1]);
                acc[r][2] = fmaf(c0, v0.z, acc[r][2]); acc[r][3] = fmaf(c0, v0.w, acc[r][3]);
                acc[r][0] = fmaf(c1, v1.x, acc[r][0]); acc[r][1] = fmaf(c1, v1.y, acc[r][1]);
                acc[r][2] = fmaf(c1, v1.z, acc[r][2]); acc[r][3] = fmaf(c1, v1.w, acc[r][3]);
                acc[r][0] = fmaf(c2, v2.x, acc[r][0]); acc[r][1] = fmaf(c2, v2.y, acc[r][1]);
                acc[r][2] = fmaf(c2, v2.z, acc[r][2]); acc[r][3] = fmaf(c2, v2.w, acc[r][3]);
                acc[r][0] = fmaf(c3, v3.x, acc[r][0]); acc[r][1] = fmaf(c3, v3.y, acc[r][1]);
                acc[r][2] = fmaf(c3, v3.z, acc[r][2]); acc[r][3] = fmaf(c3, v3.w, acc[r][3]);
            }
        }
    }
    // stage 1: butterfly over the 8 j-groups within each wave (bits 3..5)
#pragma unroll
    for (int bit = 8; bit <= 32; bit <<= 1)
#pragma unroll
        for (int r = 0; r < 8; ++r)
#pragma unroll
            for (int c = 0; c < 4; ++c)
                acc[r][c] += __shfl_xor(acc[r][c], bit, 64);
    float* red = (float*)hA;   // 16 waves x 8 dq x 32 floats = 16 KB
    if (lane < 8) {
#pragma unroll
        for (int r = 0; r < 8; ++r)
            *(float4*)&red[(wid * 8 + lane) * 32 + r * 4] =
                make_float4(acc[r][0], acc[r][1], acc[r][2], acc[r][3]);
    }
    __syncthreads();
    if (tid < 256) {
        int r = tid & 7, dd = tid >> 3;
        int dq2 = dd >> 2, dl = dd & 3;
        float o = 0.f;
#pragma unroll
        for (int w = 0; w < 16; ++w) o += red[(w * 8 + dq2) * 32 + r * 4 + dl];
        int b = bh >> 3, h = bh & 7;
        aoT[((size_t)(b * C_ + h * 32 + dd)) * N_ + n0 + r] = o;
    }
}

static const int ATTN_SMEM = 134784 + (int)sizeof(AttnMisc);

extern "C" void kernel_launch(void* const* d_in, const int* in_sizes, int n_in,
                              void* d_out, int out_size, void* d_ws, size_t ws_size,
                              hipStream_t stream)
{
    (void)in_sizes; (void)n_in; (void)out_size; (void)ws_size;
    const float* x    = (const float*)d_in[0];
    const float* y    = (const float*)d_in[1];
    const float* q_w  = (const float*)d_in[2];
    const float* q_b  = (const float*)d_in[3];
    const float* kv_w = (const float*)d_in[4];
    const float* kv_b = (const float*)d_in[5];
    const float* p_w  = (const float*)d_in[6];
    const float* p_b  = (const float*)d_in[7];
    const float* lnw  = (const float*)d_in[8];
    const float* lnb  = (const float*)d_in[9];
    const float* a1p  = (const float*)d_in[10];
    const float* a2p  = (const float*)d_in[11];
    float* out = (float*)d_out;

    float* ws = (float*)d_ws;
    const size_t PLANE = (size_t)B_ * C_ * N_;
    float* yp  = ws;
    float* yfT = ws + PLANE;
    float* qh_ = ws + 2 * PLANE;
    float* kh_ = ws + 3 * PLANE;
    float* vh_ = ws + 4 * PLANE;
    float* aoT = ws + 5 * PLANE;

    pool_kernel<<<dim3((unsigned)(PLANE / 256)), 256, 0, stream>>>(y, yp);
    ln_kernel<<<dim3(B_ * N_), 256, 0, stream>>>(yp, lnw, lnb, yfT);
    gemm_qkv<<<dim3(98, 4), 256, 0, stream>>>(x, q_w, q_b, qh_, nullptr, 0.17677669529663687f);
    gemm_qkv<<<dim3(98, 8), 256, 0, stream>>>(yfT, kv_w, kv_b, kh_, vh_, 1.0f);
    hipFuncSetAttribute(reinterpret_cast<const void*>(attn_kernel),
                        hipFuncAttributeMaxDynamicSharedMemorySize, ATTN_SMEM);
    attn_kernel<<<dim3(N_ / 8, B_ * NH_), 1024, ATTN_SMEM, stream>>>(qh_, kh_, vh_, a1p, a2p, aoT);
    gemm_proj<<<dim3(98, 4), 256, 0, stream>>>(aoT, p_w, p_b, out);
}

// Round 4
// 1785.665 us; speedup vs baseline: 1.0048x; 1.0048x over previous
//
#include <hip/hip_runtime.h>
#include <hip/hip_bf16.h>

#define B_    2
#define C_    256
#define HW_   56
#define N_    3136     // 56*56
#define NQ_   784      // N_/4 j-quads
#define NH_   8
#define D_    32
#define K1CNT 1568     // N_/2
#define K2CNT 1045     // N_//3
#define LN_EPS 1e-5f
#define SROW  3140     // padded score row (floats); 3140*4B is 16B-aligned, %32==4
#define HSTR  260      // histogram row stride; 260%32==4 -> rows spread across banks

// ---------------- helpers ----------------
__device__ inline unsigned ordf(float f) {
    unsigned u = __float_as_uint(f);
    return u ^ (((unsigned)((int)u >> 31)) | 0x80000000u);
}

// ---------------- pooling (3 avg pools summed, zero-pad, divisor k*k) -------
__global__ void pool_kernel(const float* __restrict__ y, float* __restrict__ yp)
{
    int gid = blockIdx.x * 256 + threadIdx.x;      // b*C*N + c*N + n (n fastest)
    int n  = gid % N_;
    int bc = gid / N_;
    const float* src = y + (size_t)bc * N_;
    int x0 = n % HW_, y0 = n / HW_;
    float acc = 0.f;
#pragma unroll
    for (int dy = -3; dy <= 3; ++dy) {
        int yy = y0 + dy;
        if ((unsigned)yy >= HW_) continue;
#pragma unroll
        for (int dx = -3; dx <= 3; ++dx) {
            int xx = x0 + dx;
            if ((unsigned)xx >= HW_) continue;
            float w = 1.f / 49.f;
            if (dy >= -2 && dy <= 2 && dx >= -2 && dx <= 2) w += 1.f / 25.f;
            if (dy >= -1 && dy <= 1 && dx >= -1 && dx <= 1) w += 1.f / 9.f;
            acc += w * src[yy * HW_ + xx];
        }
    }
    yp[gid] = acc;
}

// ---------------- layernorm over C, writes transposed [B,C,N] ---------------
__global__ void ln_kernel(const float* __restrict__ yp, const float* __restrict__ lnw,
                          const float* __restrict__ lnb, float* __restrict__ yfT)
{
    __shared__ float wr[8];
    __shared__ float stats[2];
    int idx = blockIdx.x;            // b*N + n
    int b = idx / N_, n = idx % N_;
    int c = threadIdx.x;
    size_t off = ((size_t)b * C_ + c) * N_ + n;
    float v = yp[off];
    float s = v, q = v * v;
    int lane = threadIdx.x & 63, wid = threadIdx.x >> 6;
#pragma unroll
    for (int d = 32; d; d >>= 1) { s += __shfl_down(s, d, 64); q += __shfl_down(q, d, 64); }
    if (lane == 0) { wr[wid] = s; wr[4 + wid] = q; }
    __syncthreads();
    if (threadIdx.x == 0) {
        float ts = wr[0] + wr[1] + wr[2] + wr[3];
        float tq = wr[4] + wr[5] + wr[6] + wr[7];
        float mu = ts * (1.f / C_);
        float var = tq * (1.f / C_) - mu * mu;
        stats[0] = mu; stats[1] = rsqrtf(var + LN_EPS);
    }
    __syncthreads();
    yfT[off] = (v - stats[0]) * stats[1] * lnw[c] + lnb[c];
}

// ---------------- GEMM: out = A(AT layout [B,C,N]) @ W[O,K]^T + bias --------
__global__ __launch_bounds__(256) void gemm_qkv(
    const float* __restrict__ A, const float* __restrict__ W,
    const float* __restrict__ bias, float* __restrict__ dst0,
    float* __restrict__ dst1, float scale)
{
    __shared__ float As[16][64];
    __shared__ float Ws[16][68];
    int tid = threadIdx.x;
    int m0 = blockIdx.x * 64;
    int b = m0 / N_, n0 = m0 % N_;
    int o0 = blockIdx.y * 64;
    const float* Ab = A + (size_t)b * C_ * N_;
    float acc[4][4] = {};
    int la_k = tid >> 4;
    int la_m = (tid & 15) * 4;
    int lw_o = tid >> 2;
    int lw_k = (tid & 3) * 4;
    int u  = tid & 15;
    int v_ = tid >> 4;
    for (int kt = 0; kt < 16; ++kt) {
        int k0 = kt * 16;
        float4 av = *(const float4*)&Ab[(size_t)(k0 + la_k) * N_ + n0 + la_m];
        float4 wv = *(const float4*)&W[(size_t)(o0 + lw_o) * C_ + k0 + lw_k];
        __syncthreads();
        *(float4*)&As[la_k][la_m] = av;
        Ws[lw_k + 0][lw_o] = wv.x; Ws[lw_k + 1][lw_o] = wv.y;
        Ws[lw_k + 2][lw_o] = wv.z; Ws[lw_k + 3][lw_o] = wv.w;
        __syncthreads();
#pragma unroll
        for (int k = 0; k < 16; ++k) {
            float4 wf = *(const float4*)&Ws[k][u * 4];
            float a0 = As[k][v_], a1 = As[k][v_ + 16], a2 = As[k][v_ + 32], a3 = As[k][v_ + 48];
            acc[0][0] += wf.x * a0; acc[0][1] += wf.x * a1; acc[0][2] += wf.x * a2; acc[0][3] += wf.x * a3;
            acc[1][0] += wf.y * a0; acc[1][1] += wf.y * a1; acc[1][2] += wf.y * a2; acc[1][3] += wf.y * a3;
            acc[2][0] += wf.z * a0; acc[2][1] += wf.z * a1; acc[2][2] += wf.z * a2; acc[2][3] += wf.z * a3;
            acc[3][0] += wf.w * a0; acc[3][1] += wf.w * a1; acc[3][2] += wf.w * a2; acc[3][3] += wf.w * a3;
        }
    }
    int oc = o0 + u * 4;
    float b0v = bias[oc], b1v = bias[oc + 1], b2v = bias[oc + 2], b3v = bias[oc + 3];
    float* dst = dst0; int c2 = oc;
    if (dst1 && oc >= C_) { dst = dst1; c2 = oc - C_; }
    int h = c2 >> 5, d0 = c2 & 31;
    size_t base = ((size_t)b * NH_ + h) * N_ * D_;
#pragma unroll
    for (int j = 0; j < 4; ++j) {
        int n = n0 + v_ + j * 16;
        float4 val;
        val.x = (acc[0][j] + b0v) * scale;
        val.y = (acc[1][j] + b1v) * scale;
        val.z = (acc[2][j] + b2v) * scale;
        val.w = (acc[3][j] + b3v) * scale;
        *(float4*)&dst[base + (size_t)n * D_ + d0] = val;
    }
}

__global__ __launch_bounds__(256) void gemm_proj(
    const float* __restrict__ A, const float* __restrict__ W,
    const float* __restrict__ bias, float* __restrict__ out)
{
    __shared__ float As[16][64];
    __shared__ float Ws[16][68];
    int tid = threadIdx.x;
    int m0 = blockIdx.x * 64;
    int b = m0 / N_, n0 = m0 % N_;
    int o0 = blockIdx.y * 64;
    const float* Ab = A + (size_t)b * C_ * N_;
    float acc[4][4] = {};
    int la_k = tid >> 4;
    int la_m = (tid & 15) * 4;
    int lw_o = tid >> 2;
    int lw_k = (tid & 3) * 4;
    int u  = tid & 15;
    int v_ = tid >> 4;
    for (int kt = 0; kt < 16; ++kt) {
        int k0 = kt * 16;
        float4 av = *(const float4*)&Ab[(size_t)(k0 + la_k) * N_ + n0 + la_m];
        float4 wv = *(const float4*)&W[(size_t)(o0 + lw_o) * C_ + k0 + lw_k];
        __syncthreads();
        *(float4*)&As[la_k][la_m] = av;
        Ws[lw_k + 0][lw_o] = wv.x; Ws[lw_k + 1][lw_o] = wv.y;
        Ws[lw_k + 2][lw_o] = wv.z; Ws[lw_k + 3][lw_o] = wv.w;
        __syncthreads();
#pragma unroll
        for (int k = 0; k < 16; ++k) {
            float4 af = *(const float4*)&As[k][u * 4];
            float w0 = Ws[k][v_], w1 = Ws[k][v_ + 16], w2 = Ws[k][v_ + 32], w3 = Ws[k][v_ + 48];
            acc[0][0] += w0 * af.x; acc[0][1] += w0 * af.y; acc[0][2] += w0 * af.z; acc[0][3] += w0 * af.w;
            acc[1][0] += w1 * af.x; acc[1][1] += w1 * af.y; acc[1][2] += w1 * af.z; acc[1][3] += w1 * af.w;
            acc[2][0] += w2 * af.x; acc[2][1] += w2 * af.y; acc[2][2] += w2 * af.z; acc[2][3] += w2 * af.w;
            acc[3][0] += w3 * af.x; acc[3][1] += w3 * af.y; acc[3][2] += w3 * af.z; acc[3][3] += w3 * af.w;
        }
    }
#pragma unroll
    for (int i = 0; i < 4; ++i) {
        int o = o0 + v_ + i * 16;
        float bb = bias[o];
        float4 val;
        val.x = acc[i][0] + bb; val.y = acc[i][1] + bb;
        val.z = acc[i][2] + bb; val.w = acc[i][3] + bb;
        *(float4*)&out[((size_t)b * C_ + o) * N_ + n0 + u * 4] = val;
    }
}

// ---------------- fused attention (1024 threads, 16 waves, 1 block/CU) ------
struct AttnMisc {
    float rowmax[8];
    unsigned prefU[16];  // accumulated radix prefix per problem (8 rows x 2 k's)
    int remK[16];        // remaining rank per problem
    float coef[16];
    float pp[2];
    float wred[256];     // 16 waves x 16 slots
};

// NOTE: the ",4" (min waves/EU) is load-bearing: with dynamic LDS the compiler
// can't see we're LDS-bound to 1 block/CU; without it, it targets 8 waves/EU,
// caps VGPRs at 64, and spills acc[][]/kq[][] to scratch (round 3: 934 MB of
// scratch WRITE_SIZE, attn 1685us). 4 waves/EU -> 128-VGPR budget, no spill.
__global__ __launch_bounds__(1024, 4) void attn_kernel(
    const float* __restrict__ qh, const float* __restrict__ kh, const float* __restrict__ vh,
    const float* __restrict__ p1p, const float* __restrict__ p2p,
    float* __restrict__ aoT)
{
    extern __shared__ char smem[];
    float*    S  = (float*)smem;                       // 8*3140 fp32   (100480 B)
    float*    qs = (float*)(smem + 100480);            // 256 fp32      (1024 B)
    unsigned* hA = (unsigned*)(smem + 101504);         // 16*260 u32    (16640 B)
    unsigned* hB = (unsigned*)(smem + 118144);         // 16*260 u32    (16640 B)
    AttnMisc* M  = (AttnMisc*)(smem + 134784);

    int tid = threadIdx.x, lane = tid & 63, wid = tid >> 6;
    int bh = blockIdx.y, n0 = blockIdx.x * 8;
    size_t bhN = (size_t)bh * N_;

    if (tid < 256) qs[tid] = qh[(bhN + n0) * D_ + tid];
    if (tid < 16) { M->prefU[tid] = 0u; M->remK[tid] = (tid & 1) ? K2CNT : K1CNT; }
    if (tid == 0) { M->pp[0] = p1p[0]; M->pp[1] = p2p[0]; }
    for (int i = tid; i < 16 * HSTR; i += 1024) hA[i] = 0u;
    __syncthreads();

    // ==== P1: scores for a 4-wide j-quad per thread, q reused across 4 j ====
    float lmax[8];
#pragma unroll
    for (int r = 0; r < 8; ++r) lmax[r] = -3.4e38f;
    if (tid < NQ_) {
        int j0 = tid * 4;
        const float* kb = kh + (bhN + j0) * D_;
        float acc[8][4] = {};
#pragma unroll
        for (int c2 = 0; c2 < 4; ++c2) {          // 8-wide chunks of K-dim
            float4 kq[4][2];
#pragma unroll
            for (int jj = 0; jj < 4; ++jj)
#pragma unroll
                for (int qi = 0; qi < 2; ++qi)
                    kq[jj][qi] = *(const float4*)&kb[jj * D_ + c2 * 8 + qi * 4];
#pragma unroll
            for (int r = 0; r < 8; ++r) {
#pragma unroll
                for (int qi = 0; qi < 2; ++qi) {
                    float4 q4 = *(const float4*)&qs[r * D_ + c2 * 8 + qi * 4];
#pragma unroll
                    for (int jj = 0; jj < 4; ++jj) {
                        acc[r][jj] = fmaf(q4.x, kq[jj][qi].x, acc[r][jj]);
                        acc[r][jj] = fmaf(q4.y, kq[jj][qi].y, acc[r][jj]);
                        acc[r][jj] = fmaf(q4.z, kq[jj][qi].z, acc[r][jj]);
                        acc[r][jj] = fmaf(q4.w, kq[jj][qi].w, acc[r][jj]);
                    }
                }
            }
        }
#pragma unroll
        for (int r = 0; r < 8; ++r) {
            *(float4*)&S[r * SROW + j0] = make_float4(acc[r][0], acc[r][1], acc[r][2], acc[r][3]);
#pragma unroll
            for (int jj = 0; jj < 4; ++jj) {
                float a = acc[r][jj];
                lmax[r] = fmaxf(lmax[r], a);
                atomicAdd(&hA[r * HSTR + (ordf(a) >> 24)], 1u);
            }
        }
    }
#pragma unroll
    for (int r = 0; r < 8; ++r) {
        float v = lmax[r];
#pragma unroll
        for (int d = 32; d; d >>= 1) v = fmaxf(v, __shfl_down(v, d, 64));
        if (lane == 0) M->wred[wid * 16 + r] = v;
    }
    __syncthreads();

    // ==== 4-level 8-bit radix select: 16 problems in parallel ====
    for (int lvl = 0; lvl < 4; ++lvl) {
        if (lvl > 0) {
            int shift = 24 - 8 * lvl;
            unsigned pf[16];
#pragma unroll
            for (int p = 0; p < 16; ++p) pf[p] = M->prefU[p];
            unsigned* hcur = (lvl & 1) ? hB : hA;
            if (tid < NQ_) {
                int j0 = tid * 4;
#pragma unroll
                for (int r = 0; r < 8; ++r) {
                    float4 sv = *(const float4*)&S[r * SROW + j0];
                    float e[4] = {sv.x, sv.y, sv.z, sv.w};
#pragma unroll
                    for (int c = 0; c < 4; ++c) {
                        unsigned u = ordf(e[c]);
                        unsigned hi = u >> (shift + 8);
                        unsigned bin = (u >> shift) & 0xFFu;
                        if (hi == pf[r * 2])     atomicAdd(&hcur[(r * 2) * HSTR + bin], 1u);
                        if (hi == pf[r * 2 + 1]) atomicAdd(&hcur[(r * 2 + 1) * HSTR + bin], 1u);
                    }
                }
            }
            __syncthreads();
        }
        {   // search (16 waves, one problem each) + zero the other hist buffer
            unsigned* hcur = (lvl & 1) ? hB : hA;
            unsigned* hoth = (lvl & 1) ? hA : hB;
            if (lvl < 3)
                for (int i = tid; i < 16 * HSTR; i += 1024) hoth[i] = 0u;
            if (lvl == 0 && tid < 8) {
                float mm = -3.4e38f;
                for (int w = 0; w < 16; ++w) mm = fmaxf(mm, M->wred[w * 16 + tid]);
                M->rowmax[tid] = mm;
            }
            int prob = wid;
            const unsigned* hh = hcur + ((lvl == 0) ? (prob >> 1) * HSTR : prob * HSTR);
            int k = M->remK[prob];
            int h0 = (int)hh[lane * 4], h1 = (int)hh[lane * 4 + 1],
                h2 = (int)hh[lane * 4 + 2], h3 = (int)hh[lane * 4 + 3];
            int ls3 = h3, ls2 = ls3 + h2, ls1 = ls2 + h1, ls0 = ls1 + h0;
            int s = ls0;
#pragma unroll
            for (int d = 1; d < 64; d <<= 1) {
                int o = __shfl_down(s, d, 64);
                if (lane + d < 64) s += o;
            }
            int after = s - ls0;     // elements in bins above this lane's 4 bins
            int G0 = ls0 + after, G1 = ls1 + after, G2 = ls2 + after, G3 = ls3 + after;
            int selb = -1, selr = 0;
            if (G0 >= k && G0 - h0 < k) { selb = lane * 4;     selr = k - (G0 - h0); }
            if (G1 >= k && G1 - h1 < k) { selb = lane * 4 + 1; selr = k - (G1 - h1); }
            if (G2 >= k && G2 - h2 < k) { selb = lane * 4 + 2; selr = k - (G2 - h2); }
            if (G3 >= k && G3 - h3 < k) { selb = lane * 4 + 3; selr = k - (G3 - h3); }
            if (selb >= 0) {
                M->prefU[prob] = (M->prefU[prob] << 8) | (unsigned)selb;
                M->remK[prob] = selr;
            }
        }
        __syncthreads();
    }

    // ==== P5: masked exp sums + signed markers (b128 in/out) ====
    unsigned t1r[8], t2r[8]; float rm[8];
#pragma unroll
    for (int r = 0; r < 8; ++r) {
        t1r[r] = M->prefU[r * 2];
        t2r[r] = M->prefU[r * 2 + 1];
        rm[r] = M->rowmax[r];
    }
    float ls1a[8] = {}, ls2a[8] = {};
    if (tid < NQ_) {
        int j0 = tid * 4;
#pragma unroll
        for (int r = 0; r < 8; ++r) {
            float4 sv = *(const float4*)&S[r * SROW + j0];
            float e[4] = {sv.x, sv.y, sv.z, sv.w};
#pragma unroll
            for (int c = 0; c < 4; ++c) {
                float a = e[c];
                unsigned u = ordf(a);
                float outv = 0.f;
                if (u >= t1r[r]) {
                    float w = __expf(a - rm[r]);
                    ls1a[r] += w;
                    if (u >= t2r[r]) { ls2a[r] += w; outv = w; }
                    else outv = -w;
                }
                e[c] = outv;
            }
            *(float4*)&S[r * SROW + j0] = make_float4(e[0], e[1], e[2], e[3]);
        }
    }
#pragma unroll
    for (int r = 0; r < 8; ++r) {
        float a1 = ls1a[r], a2 = ls2a[r];
#pragma unroll
        for (int d = 32; d; d >>= 1) { a1 += __shfl_down(a1, d, 64); a2 += __shfl_down(a2, d, 64); }
        if (lane == 0) { M->wred[wid * 16 + r * 2] = a1; M->wred[wid * 16 + r * 2 + 1] = a2; }
    }
    __syncthreads();
    if (tid < 16) {
        float ssum = 0.f;
        for (int w = 0; w < 16; ++w) ssum += M->wred[w * 16 + tid];
        M->coef[tid] = ((tid & 1) ? M->pp[1] : M->pp[0]) / ssum;
    }
    __syncthreads();

    // ==== AV: V direct from global; S b128 broadcast; coef fused at read ====
    float c12r[8], cn1r[8];
#pragma unroll
    for (int r = 0; r < 8; ++r) {
        float c1 = M->coef[r * 2], c2 = M->coef[r * 2 + 1];
        c12r[r] = c1 + c2;
        cn1r[r] = -c1;
    }
    int dq = tid & 7, g = tid >> 3;          // 128 j-groups x 8 d-quads
    const float* vb = vh + bhN * D_ + dq * 4;
    float acc[8][4] = {};
    for (int p = 0; p < 7; ++p) {
        int jq = p * 128 + g;
        if (jq < NQ_) {
            int j0 = jq * 4;
            float4 v0 = *(const float4*)&vb[(size_t)(j0 + 0) * D_];
            float4 v1 = *(const float4*)&vb[(size_t)(j0 + 1) * D_];
            float4 v2 = *(const float4*)&vb[(size_t)(j0 + 2) * D_];
            float4 v3 = *(const float4*)&vb[(size_t)(j0 + 3) * D_];
#pragma unroll
            for (int r = 0; r < 8; ++r) {
                float4 sv = *(const float4*)&S[r * SROW + j0];
                float c0 = sv.x * ((sv.x > 0.f) ? c12r[r] : cn1r[r]);
                float c1 = sv.y * ((sv.y > 0.f) ? c12r[r] : cn1r[r]);
                float c2 = sv.z * ((sv.z > 0.f) ? c12r[r] : cn1r[r]);
                float c3 = sv.w * ((sv.w > 0.f) ? c12r[r] : cn1r[r]);
                acc[r][0] = fmaf(c0, v0.x, acc[r][0]); acc[r][1] = fmaf(c0, v0.y, acc[r][1]);
                acc[r][2] = fmaf(c0, v0.z, acc[r][2]); acc[r][3] = fmaf(c0, v0.w, acc[r][3]);
                acc[r][0] = fmaf(c1, v1.x, acc[r][0]); acc[r][1] = fmaf(c1, v1.y, acc[r][1]);
                acc[r][2] = fmaf(c1, v1.z, acc[r][2]); acc[r][3] = fmaf(c1, v1.w, acc[r][3]);
                acc[r][0] = fmaf(c2, v2.x, acc[r][0]); acc[r][1] = fmaf(c2, v2.y, acc[r][1]);
                acc[r][2] = fmaf(c2, v2.z, acc[r][2]); acc[r][3] = fmaf(c2, v2.w, acc[r][3]);
                acc[r][0] = fmaf(c3, v3.x, acc[r][0]); acc[r][1] = fmaf(c3, v3.y, acc[r][1]);
                acc[r][2] = fmaf(c3, v3.z, acc[r][2]); acc[r][3] = fmaf(c3, v3.w, acc[r][3]);
            }
        }
    }
    // stage 1: butterfly over the 8 j-groups within each wave (bits 3..5)
#pragma unroll
    for (int bit = 8; bit <= 32; bit <<= 1)
#pragma unroll
        for (int r = 0; r < 8; ++r)
#pragma unroll
            for (int c = 0; c < 4; ++c)
                acc[r][c] += __shfl_xor(acc[r][c], bit, 64);
    float* red = (float*)hA;   // 16 waves x 8 dq x 32 floats = 16 KB
    if (lane < 8) {
#pragma unroll
        for (int r = 0; r < 8; ++r)
            *(float4*)&red[(wid * 8 + lane) * 32 + r * 4] =
                make_float4(acc[r][0], acc[r][1], acc[r][2], acc[r][3]);
    }
    __syncthreads();
    if (tid < 256) {
        int r = tid & 7, dd = tid >> 3;
        int dq2 = dd >> 2, dl = dd & 3;
        float o = 0.f;
#pragma unroll
        for (int w = 0; w < 16; ++w) o += red[(w * 8 + dq2) * 32 + r * 4 + dl];
        int b = bh >> 3, h = bh & 7;
        aoT[((size_t)(b * C_ + h * 32 + dd)) * N_ + n0 + r] = o;
    }
}

static const int ATTN_SMEM = 134784 + (int)sizeof(AttnMisc);

extern "C" void kernel_launch(void* const* d_in, const int* in_sizes, int n_in,
                              void* d_out, int out_size, void* d_ws, size_t ws_size,
                              hipStream_t stream)
{
    (void)in_sizes; (void)n_in; (void)out_size; (void)ws_size;
    const float* x    = (const float*)d_in[0];
    const float* y    = (const float*)d_in[1];
    const float* q_w  = (const float*)d_in[2];
    const float* q_b  = (const float*)d_in[3];
    const float* kv_w = (const float*)d_in[4];
    const float* kv_b = (const float*)d_in[5];
    const float* p_w  = (const float*)d_in[6];
    const float* p_b  = (const float*)d_in[7];
    const float* lnw  = (const float*)d_in[8];
    const float* lnb  = (const float*)d_in[9];
    const float* a1p  = (const float*)d_in[10];
    const float* a2p  = (const float*)d_in[11];
    float* out = (float*)d_out;

    float* ws = (float*)d_ws;
    const size_t PLANE = (size_t)B_ * C_ * N_;
    float* yp  = ws;
    float* yfT = ws + PLANE;
    float* qh_ = ws + 2 * PLANE;
    float* kh_ = ws + 3 * PLANE;
    float* vh_ = ws + 4 * PLANE;
    float* aoT = ws + 5 * PLANE;

    pool_kernel<<<dim3((unsigned)(PLANE / 256)), 256, 0, stream>>>(y, yp);
    ln_kernel<<<dim3(B_ * N_), 256, 0, stream>>>(yp, lnw, lnb, yfT);
    gemm_qkv<<<dim3(98, 4), 256, 0, stream>>>(x, q_w, q_b, qh_, nullptr, 0.17677669529663687f);
    gemm_qkv<<<dim3(98, 8), 256, 0, stream>>>(yfT, kv_w, kv_b, kh_, vh_, 1.0f);
    hipFuncSetAttribute(reinterpret_cast<const void*>(attn_kernel),
                        hipFuncAttributeMaxDynamicSharedMemorySize, ATTN_SMEM);
    attn_kernel<<<dim3(N_ / 8, B_ * NH_), 1024, ATTN_SMEM, stream>>>(qh_, kh_, vh_, a1p, a2p, aoT);
    gemm_proj<<<dim3(98, 4), 256, 0, stream>>>(aoT, p_w, p_b, out);
}